// Round 1
// baseline (1693.405 us; speedup 1.0000x reference)
//
#include <hip/hip_runtime.h>
#include <math.h>

#define DD 768
#define HH 16
#define DHH 48
#define NPOS 512
#define NIDX 2048
#define INV_SCALE 0.14433756729740643f   // 1/sqrt(768/16)
#define LN_EPS 1e-5f

// ---------------------------------------------------------------------------
// Batched C[512 x N] = A[512 x 768] @ B[N x 768]^T + bias   (row-major, f32)
// ---------------------------------------------------------------------------
struct GemmDesc { const float* A; const float* B; const float* bias; float* C; int N; };
struct GemmBatch { GemmDesc d[24]; };

__global__ __launch_bounds__(256) void gemm_abT(GemmBatch batch) {
  const GemmDesc de = batch.d[blockIdx.y];
  const int tm = blockIdx.x & 7;        // 8 m-tiles (M=512, BM=64)
  const int tn = blockIdx.x >> 3;       // up to 12 n-tiles (BN=64)
  if (tn * 64 >= de.N) return;
  const int m0 = tm * 64, n0 = tn * 64;

  __shared__ __align__(16) float As[16][68];   // [k][m], padded
  __shared__ __align__(16) float Bs[16][68];   // [k][n], padded

  const int tid = threadIdx.x;
  const int r = tid >> 2, q = tid & 3;        // staging: r=row(0..63), q=16B chunk
  const int ty = tid >> 4, tx = tid & 15;     // compute: 4x4 micro-tile
  float acc[4][4] = {};

  for (int k0 = 0; k0 < 768; k0 += 16) {
    __syncthreads();
    {
      const float4 av = *(const float4*)(de.A + (size_t)(m0 + r) * 768 + k0 + q * 4);
      As[q*4+0][r] = av.x; As[q*4+1][r] = av.y; As[q*4+2][r] = av.z; As[q*4+3][r] = av.w;
      float4 bv = make_float4(0.f, 0.f, 0.f, 0.f);
      if (n0 + r < de.N) bv = *(const float4*)(de.B + (size_t)(n0 + r) * 768 + k0 + q * 4);
      Bs[q*4+0][r] = bv.x; Bs[q*4+1][r] = bv.y; Bs[q*4+2][r] = bv.z; Bs[q*4+3][r] = bv.w;
    }
    __syncthreads();
#pragma unroll
    for (int kk = 0; kk < 16; ++kk) {
      const float4 a = *(const float4*)&As[kk][ty * 4];
      const float4 b = *(const float4*)&Bs[kk][tx * 4];
      const float aa[4] = {a.x, a.y, a.z, a.w};
      const float bb[4] = {b.x, b.y, b.z, b.w};
#pragma unroll
      for (int i = 0; i < 4; ++i)
#pragma unroll
        for (int j = 0; j < 4; ++j) acc[i][j] += aa[i] * bb[j];
    }
  }

  if (n0 + tx * 4 < de.N) {
    float4 bias = make_float4(0.f, 0.f, 0.f, 0.f);
    if (de.bias) bias = *(const float4*)(de.bias + n0 + tx * 4);
#pragma unroll
    for (int i = 0; i < 4; ++i) {
      float4 o;
      o.x = acc[i][0] + bias.x; o.y = acc[i][1] + bias.y;
      o.z = acc[i][2] + bias.z; o.w = acc[i][3] + bias.w;
      *(float4*)(de.C + (size_t)(m0 + ty * 4 + i) * de.N + n0 + tx * 4) = o;
    }
  }
}

// ---------------------------------------------------------------------------
// Histograms of fpos / tpos per segment: CNT[b*2+which][512]
// ---------------------------------------------------------------------------
__global__ void hist_kernel(const int* __restrict__ fpos, const int* __restrict__ tpos,
                            int* __restrict__ CNT) {
  const int blk = blockIdx.x;           // b*2 + which
  const int b = blk >> 1, which = blk & 1;
  const int* src = (which ? tpos : fpos) + b * NIDX;
  __shared__ int c[NPOS];
  for (int i = threadIdx.x; i < NPOS; i += blockDim.x) c[i] = 0;
  __syncthreads();
  for (int i = threadIdx.x; i < NIDX; i += blockDim.x)
    atomicAdd(&c[src[i] & (NPOS - 1)], 1);
  __syncthreads();
  for (int i = threadIdx.x; i < NPOS; i += blockDim.x) CNT[blk * NPOS + i] = c[i];
}

// ---------------------------------------------------------------------------
// Fused scores + count-weighted softmax + P@V for one (b, dir, head, 32-row tile)
// S[i][j] = sum_d Q[pf0+i][d]*mix[h][d]*K[j][d]  over the 512-unique-pos grid.
// ---------------------------------------------------------------------------
__global__ __launch_bounds__(256) void attn_fused(
    const float* __restrict__ Qb, const float* __restrict__ Kb,
    const float* __restrict__ Vb, const float* __restrict__ CBb,
    const float* __restrict__ mix_q, const float* __restrict__ mix_c,
    const int* __restrict__ CNT, float* __restrict__ CTX) {
  const int idx = blockIdx.x;
  const int pft = idx & 15;             // 16 tiles of 32 rows
  const int h   = (idx >> 4) & 15;
  const int pd  = idx >> 8;             // b*2+dir, 0..5
  const int dir = pd & 1;
  const int pf0 = pft * 32;

  const float* Q  = Qb + (size_t)pd * NPOS * DD;
  const float* K  = Kb + (size_t)pd * NPOS * DD;
  const float* V  = Vb + (size_t)pd * NPOS * DD;
  const float* CB = CBb + (size_t)pd * NPOS * HH;
  const float* mix = (dir ? mix_c : mix_q) + h * DD;
  const int* cnt = CNT + ((pd & ~1) + (1 - dir)) * NPOS;  // to-side counts
  float* ctxo = CTX + (size_t)pd * NPOS * DD;

  __shared__ __align__(16) float S[32][520];   // padded: stride 520 => 2-way max
  __shared__ __align__(16) float Qs[16][36];   // [k][i]
  __shared__ __align__(16) float Ks[16][68];   // [k][j]
  __shared__ float cbs[NPOS];
  __shared__ float cw[NPOS];
  __shared__ float rowl[32];

  const int tid = threadIdx.x;
  for (int p = tid; p < NPOS; p += 256) {
    cbs[p] = CB[p * HH + h];
    cw[p]  = (float)cnt[p];
  }
  __syncthreads();

  const int ty = tid >> 4, tx = tid & 15;

  // ---- phase 1: S[32][512], j in tiles of 64, k in tiles of 16 ----
  for (int jt = 0; jt < 8; ++jt) {
    const int j0 = jt * 64;
    float acc[2][4] = {};
    for (int k0 = 0; k0 < DD; k0 += 16) {
      __syncthreads();
      if (tid < 128) {
        const int rr = tid >> 2, qq = tid & 3;
        const float4 qv = *(const float4*)(Q + (size_t)(pf0 + rr) * DD + k0 + qq * 4);
        const float4 mv = *(const float4*)(mix + k0 + qq * 4);
        Qs[qq*4+0][rr] = qv.x * mv.x; Qs[qq*4+1][rr] = qv.y * mv.y;
        Qs[qq*4+2][rr] = qv.z * mv.z; Qs[qq*4+3][rr] = qv.w * mv.w;
      }
      {
        const int rr = tid >> 2, qq = tid & 3;
        const float4 kv = *(const float4*)(K + (size_t)(j0 + rr) * DD + k0 + qq * 4);
        Ks[qq*4+0][rr] = kv.x; Ks[qq*4+1][rr] = kv.y;
        Ks[qq*4+2][rr] = kv.z; Ks[qq*4+3][rr] = kv.w;
      }
      __syncthreads();
#pragma unroll
      for (int kk = 0; kk < 16; ++kk) {
        const float2 a = *(const float2*)&Qs[kk][ty * 2];
        const float4 b = *(const float4*)&Ks[kk][tx * 4];
        acc[0][0] += a.x * b.x; acc[0][1] += a.x * b.y;
        acc[0][2] += a.x * b.z; acc[0][3] += a.x * b.w;
        acc[1][0] += a.y * b.x; acc[1][1] += a.y * b.y;
        acc[1][2] += a.y * b.z; acc[1][3] += a.y * b.w;
      }
    }
#pragma unroll
    for (int ii = 0; ii < 2; ++ii)
#pragma unroll
      for (int jj = 0; jj < 4; ++jj)
        S[ty * 2 + ii][j0 + tx * 4 + jj] = acc[ii][jj];
  }
  __syncthreads();

  // ---- phase 2: count-weighted softmax per row ----
  {
    const int i = tid >> 3, s = tid & 7;
    float m = -1e30f;
#pragma unroll 4
    for (int j = s; j < NPOS; j += 8) {
      const float v = (S[i][j] + cbs[j]) * INV_SCALE;
      S[i][j] = v;
      m = fmaxf(m, v);
    }
    m = fmaxf(m, __shfl_xor(m, 1));
    m = fmaxf(m, __shfl_xor(m, 2));
    m = fmaxf(m, __shfl_xor(m, 4));
    float l = 0.f;
#pragma unroll 4
    for (int j = s; j < NPOS; j += 8) {
      const float p = cw[j] * __expf(S[i][j] - m);
      S[i][j] = p;
      l += p;
    }
    l += __shfl_xor(l, 1);
    l += __shfl_xor(l, 2);
    l += __shfl_xor(l, 4);
    if (s == 0) rowl[i] = l;
  }
  __syncthreads();

  // ---- phase 3: ctx[i][c] = (1/l_i) sum_j P[i][j] * V[j][h*48+c] ----
  if (tid < 192) {
    const int rr = tid / 48, c = tid % 48;   // rr 0..3, rows rr,rr+4,...,rr+28
    float accv[8] = {};
    for (int j = 0; j < NPOS; ++j) {
      const float vv = V[(size_t)j * DD + h * DHH + c];
#pragma unroll
      for (int qq = 0; qq < 8; ++qq) accv[qq] += S[rr + qq * 4][j] * vv;
    }
#pragma unroll
    for (int qq = 0; qq < 8; ++qq) {
      const int i = rr + qq * 4;
      ctxo[(size_t)(pf0 + i) * DD + h * DHH + c] = accv[qq] / rowl[i];
    }
  }
}

// ---------------------------------------------------------------------------
// Residual + LayerNorm + count-weighted mean -> out[b][dir*768 .. +768]
// ---------------------------------------------------------------------------
__global__ __launch_bounds__(256) void ln_mean_kernel(
    const float* __restrict__ hs, const float* __restrict__ XB,
    const int* __restrict__ CNT,
    const float* __restrict__ lng0, const float* __restrict__ lnb0,
    const float* __restrict__ lng1, const float* __restrict__ lnb1,
    float* __restrict__ out) {
  const int blk = blockIdx.x;          // (b*2+dir)*4 + chunk
  const int chunk = blk & 3;
  const int pd = blk >> 2;
  const int b = pd >> 1, dir = pd & 1;
  const float* lng = dir ? lng1 : lng0;
  const float* lnb = dir ? lnb1 : lnb0;
  const int* cnt = CNT + pd * NPOS;    // from-side counts (dir0->fpos, dir1->tpos)
  const float* hb = hs + (size_t)b * NPOS * DD;
  const float* xb = XB + (size_t)pd * NPOS * DD;

  __shared__ float wacc[4][DD];
  const int tid = threadIdx.x;
  const int wave = tid >> 6, lane = tid & 63;
  for (int d0 = tid; d0 < 4 * DD; d0 += 256) ((float*)wacc)[d0] = 0.f;
  __syncthreads();

  float lg[12], lb[12];
#pragma unroll
  for (int qd = 0; qd < 12; ++qd) {
    lg[qd] = lng[lane + qd * 64];
    lb[qd] = lnb[lane + qd * 64];
  }

  for (int rr = 0; rr < 32; ++rr) {
    const int p = chunk * 128 + wave * 32 + rr;
    float x[12];
    float s = 0.f, ss = 0.f;
#pragma unroll
    for (int qd = 0; qd < 12; ++qd) {
      const int d0 = lane + qd * 64;
      const float xv = hb[(size_t)p * DD + d0] + xb[(size_t)p * DD + d0];
      x[qd] = xv; s += xv; ss += xv * xv;
    }
#pragma unroll
    for (int o = 1; o < 64; o <<= 1) {
      s += __shfl_xor(s, o);
      ss += __shfl_xor(ss, o);
    }
    const float mu = s * (1.f / 768.f);
    const float var = ss * (1.f / 768.f) - mu * mu;
    const float rstd = rsqrtf(var + LN_EPS);
    const float w = (float)cnt[p];
    if (w != 0.f) {
#pragma unroll
      for (int qd = 0; qd < 12; ++qd) {
        const int d0 = lane + qd * 64;
        wacc[wave][d0] += w * (lg[qd] * (x[qd] - mu) * rstd + lb[qd]);
      }
    }
  }
  __syncthreads();
  for (int d0 = tid; d0 < DD; d0 += 256) {
    const float t = wacc[0][d0] + wacc[1][d0] + wacc[2][d0] + wacc[3][d0];
    atomicAdd(&out[b * 1536 + dir * 768 + d0], t * (1.f / 2048.f));
  }
}

// ---------------------------------------------------------------------------
extern "C" void kernel_launch(void* const* d_in, const int* in_sizes, int n_in,
                              void* d_out, int out_size, void* d_ws, size_t ws_size,
                              hipStream_t stream) {
  const float* hs  = (const float*)d_in[0];
  const int* fpos  = (const int*)d_in[1];
  const int* tpos  = (const int*)d_in[2];

  // per paramset p: base = 3 + p*10: Wq, Wk, Wcb, Wv, Wd, mix, bv, bd, lng, lnb
  const float* Wq[2];  const float* Wk[2];  const float* Wcb[2]; const float* Wv[2];
  const float* Wd[2];  const float* mixp[2];
  const float* bv[2];  const float* bd[2];  const float* lng[2]; const float* lnb[2];
  for (int p = 0; p < 2; ++p) {
    const int base = 3 + p * 10;
    Wq[p]   = (const float*)d_in[base + 0];
    Wk[p]   = (const float*)d_in[base + 1];
    Wcb[p]  = (const float*)d_in[base + 2];
    Wv[p]   = (const float*)d_in[base + 3];
    Wd[p]   = (const float*)d_in[base + 4];
    mixp[p] = (const float*)d_in[base + 5];
    bv[p]   = (const float*)d_in[base + 6];
    bd[p]   = (const float*)d_in[base + 7];
    lng[p]  = (const float*)d_in[base + 8];
    lnb[p]  = (const float*)d_in[base + 9];
  }

  // workspace layout (floats)
  const size_t PS = (size_t)6 * NPOS * DD;       // 2,359,296 floats per big buffer
  float* w    = (float*)d_ws;
  float* Qb   = w;
  float* Kb   = Qb + PS;
  float* Vb   = Kb + PS;
  float* CBb  = Vb + PS;                         // 6*512*16 = 49152
  float* CTXb = CBb + (size_t)6 * NPOS * HH;
  float* XBb  = CTXb + PS;
  int*   CNTb = (int*)(XBb + PS);                // 6*512 ints

  hipMemsetAsync(d_out, 0, (size_t)out_size * sizeof(float), stream);
  hist_kernel<<<6, 256, 0, stream>>>(fpos, tpos, CNTb);

  // projections: Q/K/V/CB for each (b, pset)
  GemmBatch gb{};
  int n = 0;
  for (int b = 0; b < 3; ++b)
    for (int p = 0; p < 2; ++p) {
      const float* A = hs + (size_t)b * NPOS * DD;
      const size_t off = (size_t)(b * 2 + p) * NPOS * DD;
      gb.d[n++] = GemmDesc{A, Wq[p],  nullptr, Qb + off, 768};
      gb.d[n++] = GemmDesc{A, Wk[p],  nullptr, Kb + off, 768};
      gb.d[n++] = GemmDesc{A, Wv[p],  bv[p],   Vb + off, 768};
      gb.d[n++] = GemmDesc{A, Wcb[p], nullptr, CBb + (size_t)(b * 2 + p) * NPOS * HH, 16};
    }
  gemm_abT<<<dim3(96, 24), 256, 0, stream>>>(gb);

  attn_fused<<<1536, 256, 0, stream>>>(Qb, Kb, Vb, CBb, mixp[0], mixp[1], CNTb, CTXb);

  // output projection Wd per (b, dir)
  GemmBatch gd{};
  for (int b = 0; b < 3; ++b)
    for (int p = 0; p < 2; ++p) {
      const int pd = b * 2 + p;
      const size_t off = (size_t)pd * NPOS * DD;
      gd.d[pd] = GemmDesc{CTXb + off, Wd[p], bd[p], XBb + off, 768};
    }
  gemm_abT<<<dim3(96, 6), 256, 0, stream>>>(gd);

  ln_mean_kernel<<<24, 256, 0, stream>>>(hs, XBb, CNTb, lng[0], lnb[0], lng[1], lnb[1],
                                         (float*)d_out);
}

// Round 2
// 392.904 us; speedup vs baseline: 4.3100x; 4.3100x over previous
//
#include <hip/hip_runtime.h>
#include <math.h>

#define DD 768
#define HH 16
#define DHH 48
#define NPOS 512
#define NIDX 2048
#define INV_SCALE 0.14433756729740643f   // 1/sqrt(768/16)
#define LN_EPS 1e-5f

typedef __bf16 bf16_t;
typedef __bf16 bf16x8 __attribute__((ext_vector_type(8)));
typedef float f32x4 __attribute__((ext_vector_type(4)));

__device__ __forceinline__ void g2lds16(const void* g, void* l) {
  __builtin_amdgcn_global_load_lds((const __attribute__((address_space(1))) void*)g,
                                   (__attribute__((address_space(3))) void*)l, 16, 0, 0);
}

// ---------------------------------------------------------------------------
// Histograms of fpos / tpos per segment: CNT[b*2+which][512]
// ---------------------------------------------------------------------------
__global__ void hist_kernel(const int* __restrict__ fpos, const int* __restrict__ tpos,
                            int* __restrict__ CNT) {
  const int blk = blockIdx.x;           // b*2 + which
  const int b = blk >> 1, which = blk & 1;
  const int* src = (which ? tpos : fpos) + b * NIDX;
  __shared__ int c[NPOS];
  for (int i = threadIdx.x; i < NPOS; i += blockDim.x) c[i] = 0;
  __syncthreads();
  for (int i = threadIdx.x; i < NIDX; i += blockDim.x)
    atomicAdd(&c[src[i] & (NPOS - 1)], 1);
  __syncthreads();
  for (int i = threadIdx.x; i < NPOS; i += blockDim.x) CNT[blk * NPOS + i] = c[i];
}

// ---------------------------------------------------------------------------
// Batched fp32 -> bf16 conversion
// ---------------------------------------------------------------------------
struct CvtDesc { const float* src; bf16_t* dst; int n8; };
struct CvtBatch { CvtDesc d[9]; };

__global__ __launch_bounds__(256) void cvt_bf16(CvtBatch cb) {
  const CvtDesc de = cb.d[blockIdx.y];
  for (int i = blockIdx.x * 256 + threadIdx.x; i < de.n8; i += gridDim.x * 256) {
    const f32x4 a = *(const f32x4*)(de.src + (size_t)i * 8);
    const f32x4 b = *(const f32x4*)(de.src + (size_t)i * 8 + 4);
    bf16_t t[8];
#pragma unroll
    for (int e = 0; e < 4; ++e) { t[e] = (bf16_t)a[e]; t[4 + e] = (bf16_t)b[e]; }
    *(bf16x8*)(de.dst + (size_t)i * 8) = *(bf16x8*)t;
  }
}

// ---------------------------------------------------------------------------
// Content bias: cbG[pd][t][h] = hs[b][t] . Wcb[ps][h]
// ---------------------------------------------------------------------------
__global__ __launch_bounds__(256) void cb_kernel(const float* __restrict__ hs,
                                                 const float* __restrict__ Wcb0,
                                                 const float* __restrict__ Wcb1,
                                                 float* __restrict__ cbG) {
  const int g = blockIdx.x;               // 6*32
  const int pd = g >> 5, t0 = (g & 31) * 16;
  const int b = pd >> 1;
  const float* W = (pd & 1) ? Wcb1 : Wcb0;
  const int tl = threadIdx.x >> 4, hh = threadIdx.x & 15;
  const float* hrow = hs + ((size_t)b * NPOS + t0 + tl) * DD;
  const float* wrow = W + hh * DD;
  float s = 0.f;
  for (int k = 0; k < DD; k += 4) {
    const f32x4 a = *(const f32x4*)(hrow + k);
    const f32x4 bq = *(const f32x4*)(wrow + k);
    s += a[0] * bq[0] + a[1] * bq[1] + a[2] * bq[2] + a[3] * bq[3];
  }
  cbG[((size_t)pd * NPOS + t0 + tl) * HH + hh] = s;
}

// ---------------------------------------------------------------------------
// MFMA GEMM: C[512 x 768] = A[512 x 768]bf16 @ B[768 x 768]bf16^T + bias
// 128x128 tile, BK=32, global_load_lds staging (m97 pattern)
// ---------------------------------------------------------------------------
struct MDesc { const bf16_t* A; const bf16_t* B; const float* bias; void* C; int out_bf16; };
struct MBatch { MDesc d[18]; };

__global__ __launch_bounds__(256, 2) void mfma_gemm(MBatch batch) {
  const MDesc de = batch.d[blockIdx.y];
  const int mt = blockIdx.x & 3, nt = blockIdx.x >> 2;   // 4 x 6
  const int m0 = mt * 128, n0 = nt * 128;

  __shared__ bf16_t At[4096];   // [128][32] packed, 64B rows
  __shared__ bf16_t Bt[4096];

  const int tid = threadIdx.x;
  const int w = tid >> 6, lane = tid & 63;
  const int wm = w >> 1, wn = w & 1;
  const int lm = lane & 15, lq = lane >> 4;

  f32x4 acc[4][4] = {};

  for (int k0 = 0; k0 < 768; k0 += 32) {
    __syncthreads();
    {
      const int lqq = lane & 3, lr = lane >> 2;
#pragma unroll
      for (int i = 0; i < 2; ++i) {
        const int issue = w + i * 4;            // 0..7
        const int row = issue * 16 + lr;
        g2lds16(de.A + (size_t)(m0 + row) * 768 + k0 + lqq * 8, At + issue * 512);
        g2lds16(de.B + (size_t)(n0 + row) * 768 + k0 + lqq * 8, Bt + issue * 512);
      }
    }
    __syncthreads();
    bf16x8 af[4], bfr[4];
#pragma unroll
    for (int f = 0; f < 4; ++f) {
      af[f] = *(const bf16x8*)(At + (wm * 64 + f * 16 + lm) * 32 + lq * 8);
      bfr[f] = *(const bf16x8*)(Bt + (wn * 64 + f * 16 + lm) * 32 + lq * 8);
    }
#pragma unroll
    for (int i = 0; i < 4; ++i)
#pragma unroll
      for (int j = 0; j < 4; ++j)
        acc[i][j] = __builtin_amdgcn_mfma_f32_16x16x32_bf16(af[i], bfr[j], acc[i][j], 0, 0, 0);
  }

#pragma unroll
  for (int i = 0; i < 4; ++i) {
    const int rbase = m0 + wm * 64 + i * 16 + lq * 4;
#pragma unroll
    for (int j = 0; j < 4; ++j) {
      const int c = n0 + wn * 64 + j * 16 + lm;
      const float bv = de.bias ? de.bias[c] : 0.f;
#pragma unroll
      for (int r = 0; r < 4; ++r) {
        const float v = acc[i][j][r] + bv;
        if (de.out_bf16) ((bf16_t*)de.C)[(size_t)(rbase + r) * 768 + c] = (bf16_t)v;
        else             ((float*)de.C)[(size_t)(rbase + r) * 768 + c] = v;
      }
    }
  }
}

// ---------------------------------------------------------------------------
// Transpose V fp32 [pd][t][d] -> Vt bf16 [pd][d][t]
// ---------------------------------------------------------------------------
__global__ __launch_bounds__(256) void vtrans(const float* __restrict__ V,
                                              bf16_t* __restrict__ Vt) {
  const int g = blockIdx.x;               // 6*24*16
  const int tt = g & 15;
  const int rem = g >> 4;
  const int dt = rem % 24, pd = rem / 24;
  const int t0 = tt * 32, d0 = dt * 32;
  __shared__ float tile[32][33];
  const int c = threadIdx.x & 31, r0 = threadIdx.x >> 5;
#pragma unroll
  for (int i = 0; i < 4; ++i) {
    const int r = r0 + i * 8;
    tile[c][r] = V[((size_t)pd * NPOS + t0 + r) * DD + d0 + c];
  }
  __syncthreads();
#pragma unroll
  for (int i = 0; i < 4; ++i) {
    const int r = r0 + i * 8;
    Vt[((size_t)pd * DD + d0 + r) * NPOS + t0 + c] = (bf16_t)tile[r][c];
  }
}

// ---------------------------------------------------------------------------
// Fused MFMA attention per (pd, h, 128-row f-tile):
// scores (MFMA) -> count-weighted exp (no max: |logit| <= ~2) -> P bf16 to LDS
// -> P@[V^T | 1] via MFMA (col 48 of D = row sum l) -> ctx = pv/l -> bf16 out
// ---------------------------------------------------------------------------
__global__ __launch_bounds__(256, 2) void attn_mfma(
    const float* __restrict__ Qf, const bf16_t* __restrict__ Kb,
    const bf16_t* __restrict__ Vt, const float* __restrict__ cbG,
    const int* __restrict__ CNT, const float* __restrict__ mix0,
    const float* __restrict__ mix1, bf16_t* __restrict__ CTX) {
  const int bid = blockIdx.x;             // 6*16*4 = 384
  const int ft = bid & 3, h = (bid >> 2) & 15, pd = bid >> 6;
  const int dir = pd & 1;
  const int f0 = ft * 128;

  __shared__ bf16_t At[128 * 40];         // [f][k] stride 40 (pad)
  __shared__ bf16_t Bt[128 * 40];         // [t][k] stride 40
  __shared__ bf16_t P[128 * 136];         // [f][j] stride 136
  __shared__ bf16_t Vs[64 * 136];         // [c][j] stride 136; row48 = ones
  __shared__ float mixs[768];
  __shared__ float cbss[512];
  __shared__ float cw[512];
  __shared__ float rowl[128];

  const int tid = threadIdx.x;
  const int w = tid >> 6, lane = tid & 63;
  const float* Qb = Qf + (size_t)pd * NPOS * DD;
  const bf16_t* Kp = Kb + (size_t)pd * NPOS * DD;
  const bf16_t* Vp = Vt + (size_t)pd * DD * NPOS + (size_t)h * DHH * NPOS;
  const float* mix = (dir ? mix1 : mix0) + h * DD;
  const int* cnt = CNT + ((pd & ~1) + (1 - dir)) * NPOS;  // to-side counts

  for (int i = tid; i < 768; i += 256) mixs[i] = mix[i];
  for (int i = tid; i < 512; i += 256) {
    cbss[i] = cbG[((size_t)pd * NPOS + i) * HH + h] * INV_SCALE;
    cw[i] = (float)cnt[i];
  }
  for (int i = tid; i < 16 * 136; i += 256) {
    const int r = i / 136, c = i % 136;
    Vs[(48 + r) * 136 + c] = (bf16_t)((r == 0 && c < 128) ? 1.f : 0.f);
  }
  __syncthreads();

  const int wm = w >> 1, wn = w & 1;
  const int lm = lane & 15, lq = lane >> 4;
  const int sr = tid >> 1, sh = tid & 1;   // staging: row 0..127, 16-elem half

  f32x4 pv[2][4] = {};

  for (int jt = 0; jt < 4; ++jt) {
    const int j0 = jt * 128;
    f32x4 sa[4][4] = {};

    for (int k0 = 0; k0 < 768; k0 += 32) {
      __syncthreads();
      {
        // stage A = Q * mix -> bf16 (VALU; overlaps MFMA pipe across waves)
        const float* qrow = Qb + (size_t)(f0 + sr) * DD + k0 + sh * 16;
        const float* mrow = mixs + k0 + sh * 16;
        bf16_t tmp[16];
#pragma unroll
        for (int u = 0; u < 4; ++u) {
          const f32x4 qv = *(const f32x4*)(qrow + u * 4);
          const f32x4 mv = *(const f32x4*)(mrow + u * 4);
#pragma unroll
          for (int e = 0; e < 4; ++e) tmp[u * 4 + e] = (bf16_t)(qv[e] * mv[e]);
        }
        *(bf16x8*)(At + sr * 40 + sh * 16) = *(bf16x8*)tmp;
        *(bf16x8*)(At + sr * 40 + sh * 16 + 8) = *(bf16x8*)(tmp + 8);
        // stage B = K bf16 (straight copy, padded stride)
        const bf16x8* krow = (const bf16x8*)(Kp + (size_t)(j0 + sr) * DD + k0 + sh * 16);
        *(bf16x8*)(Bt + sr * 40 + sh * 16) = krow[0];
        *(bf16x8*)(Bt + sr * 40 + sh * 16 + 8) = krow[1];
      }
      __syncthreads();
      bf16x8 af[4], bfr[4];
#pragma unroll
      for (int f = 0; f < 4; ++f) {
        af[f] = *(const bf16x8*)(At + (wm * 64 + f * 16 + lm) * 40 + lq * 8);
        bfr[f] = *(const bf16x8*)(Bt + (wn * 64 + f * 16 + lm) * 40 + lq * 8);
      }
#pragma unroll
      for (int i = 0; i < 4; ++i)
#pragma unroll
        for (int j = 0; j < 4; ++j)
          sa[i][j] = __builtin_amdgcn_mfma_f32_16x16x32_bf16(af[i], bfr[j], sa[i][j], 0, 0, 0);
    }
    __syncthreads();

    // transform: p = cnt * exp((s+cb)/SCALE)  (no max needed: |logit| <= ~2)
#pragma unroll
    for (int j = 0; j < 4; ++j) {
      const int col = wn * 64 + j * 16 + lm;
      const float cb = cbss[j0 + col];
      const float cv = cw[j0 + col];
#pragma unroll
      for (int i = 0; i < 4; ++i) {
        const int rbase = wm * 64 + i * 16 + lq * 4;
#pragma unroll
        for (int r = 0; r < 4; ++r) {
          const float p = cv * __expf(sa[i][j][r] * INV_SCALE + cb);
          P[(rbase + r) * 136 + col] = (bf16_t)p;
        }
      }
    }
    // stage V^T tile rows 0..47 (c-local), cols j0..j0+127
    for (int i = tid; i < 48 * 16; i += 256) {
      const int r = i >> 4, cc = i & 15;
      *(bf16x8*)(Vs + r * 136 + cc * 8) = *(const bf16x8*)(Vp + (size_t)r * NPOS + j0 + cc * 8);
    }
    __syncthreads();

    // PV: wave handles 32 f-rows; acc col 48 accumulates l
#pragma unroll
    for (int kk = 0; kk < 4; ++kk) {
      bf16x8 pa[2], pb[4];
#pragma unroll
      for (int i = 0; i < 2; ++i)
        pa[i] = *(const bf16x8*)(P + (w * 32 + i * 16 + lm) * 136 + kk * 32 + lq * 8);
#pragma unroll
      for (int j = 0; j < 4; ++j)
        pb[j] = *(const bf16x8*)(Vs + (j * 16 + lm) * 136 + kk * 32 + lq * 8);
#pragma unroll
      for (int i = 0; i < 2; ++i)
#pragma unroll
        for (int j = 0; j < 4; ++j)
          pv[i][j] = __builtin_amdgcn_mfma_f32_16x16x32_bf16(pa[i], pb[j], pv[i][j], 0, 0, 0);
    }
  }

  // epilogue: l = pv[:,3] col 48 (lanes lm==0), then ctx = pv/l
  if (lm == 0) {
#pragma unroll
    for (int i = 0; i < 2; ++i)
#pragma unroll
      for (int r = 0; r < 4; ++r)
        rowl[w * 32 + i * 16 + lq * 4 + r] = pv[i][3][r];
  }
  __syncthreads();
#pragma unroll
  for (int i = 0; i < 2; ++i) {
    const int rbase = w * 32 + i * 16 + lq * 4;
#pragma unroll
    for (int j = 0; j < 3; ++j) {
      const int c = j * 16 + lm;
#pragma unroll
      for (int r = 0; r < 4; ++r) {
        const float l = rowl[rbase + r];
        CTX[((size_t)pd * NPOS + f0 + rbase + r) * DD + h * DHH + c] = (bf16_t)(pv[i][j][r] / l);
      }
    }
  }
}

// ---------------------------------------------------------------------------
// Residual + LayerNorm + count-weighted mean -> out[b][dir*768 .. +768]
// ---------------------------------------------------------------------------
__global__ __launch_bounds__(256) void ln_mean_kernel(
    const float* __restrict__ hs, const float* __restrict__ XB,
    const int* __restrict__ CNT,
    const float* __restrict__ lng0, const float* __restrict__ lnb0,
    const float* __restrict__ lng1, const float* __restrict__ lnb1,
    float* __restrict__ out) {
  const int blk = blockIdx.x;          // (b*2+dir)*4 + chunk
  const int chunk = blk & 3;
  const int pd = blk >> 2;
  const int b = pd >> 1, dir = pd & 1;
  const float* lng = dir ? lng1 : lng0;
  const float* lnb = dir ? lnb1 : lnb0;
  const int* cnt = CNT + pd * NPOS;    // from-side counts
  const float* hb = hs + (size_t)b * NPOS * DD;
  const float* xb = XB + (size_t)pd * NPOS * DD;

  __shared__ float wacc[4][DD];
  const int tid = threadIdx.x;
  const int wave = tid >> 6, lane = tid & 63;
  for (int d0 = tid; d0 < 4 * DD; d0 += 256) ((float*)wacc)[d0] = 0.f;
  __syncthreads();

  float lg[12], lb[12];
#pragma unroll
  for (int qd = 0; qd < 12; ++qd) {
    lg[qd] = lng[lane + qd * 64];
    lb[qd] = lnb[lane + qd * 64];
  }

  for (int rr = 0; rr < 32; ++rr) {
    const int p = chunk * 128 + wave * 32 + rr;
    float x[12];
    float s = 0.f, ss = 0.f;
#pragma unroll
    for (int qd = 0; qd < 12; ++qd) {
      const int d0 = lane + qd * 64;
      const float xv = hb[(size_t)p * DD + d0] + xb[(size_t)p * DD + d0];
      x[qd] = xv; s += xv; ss += xv * xv;
    }
#pragma unroll
    for (int o = 1; o < 64; o <<= 1) {
      s += __shfl_xor(s, o);
      ss += __shfl_xor(ss, o);
    }
    const float mu = s * (1.f / 768.f);
    const float var = ss * (1.f / 768.f) - mu * mu;
    const float rstd = rsqrtf(var + LN_EPS);
    const float wgt = (float)cnt[p];
    if (wgt != 0.f) {
#pragma unroll
      for (int qd = 0; qd < 12; ++qd) {
        const int d0 = lane + qd * 64;
        wacc[wave][d0] += wgt * (lg[qd] * (x[qd] - mu) * rstd + lb[qd]);
      }
    }
  }
  __syncthreads();
  for (int d0 = tid; d0 < DD; d0 += 256) {
    const float t = wacc[0][d0] + wacc[1][d0] + wacc[2][d0] + wacc[3][d0];
    atomicAdd(&out[b * 1536 + dir * 768 + d0], t * (1.f / 2048.f));
  }
}

// ---------------------------------------------------------------------------
extern "C" void kernel_launch(void* const* d_in, const int* in_sizes, int n_in,
                              void* d_out, int out_size, void* d_ws, size_t ws_size,
                              hipStream_t stream) {
  const float* hs  = (const float*)d_in[0];
  const int* fpos  = (const int*)d_in[1];
  const int* tpos  = (const int*)d_in[2];

  const float* Wq[2]; const float* Wk[2]; const float* Wcb[2]; const float* Wv[2];
  const float* Wd[2]; const float* mixp[2];
  const float* bv[2]; const float* bd[2]; const float* lng[2]; const float* lnb[2];
  for (int p = 0; p < 2; ++p) {
    const int base = 3 + p * 10;
    Wq[p]   = (const float*)d_in[base + 0];
    Wk[p]   = (const float*)d_in[base + 1];
    Wcb[p]  = (const float*)d_in[base + 2];
    Wv[p]   = (const float*)d_in[base + 3];
    Wd[p]   = (const float*)d_in[base + 4];
    mixp[p] = (const float*)d_in[base + 5];
    bv[p]   = (const float*)d_in[base + 6];
    bd[p]   = (const float*)d_in[base + 7];
    lng[p]  = (const float*)d_in[base + 8];
    lnb[p]  = (const float*)d_in[base + 9];
  }

  // workspace layout (bytes, 256-aligned)
  char* wsp = (char*)d_ws;
  size_t off = 0;
  auto alloc = [&](size_t bytes) { char* p = wsp + off; off = (off + bytes + 255) & ~(size_t)255; return p; };
  bf16_t* hsb  = (bf16_t*)alloc((size_t)3 * NPOS * DD * 2);
  bf16_t* Wb   = (bf16_t*)alloc((size_t)8 * DD * DD * 2);   // Wq0,Wk0,Wv0,Wd0,Wq1,Wk1,Wv1,Wd1
  float*  Qf   = (float*) alloc((size_t)6 * NPOS * DD * 4);
  bf16_t* Kb   = (bf16_t*)alloc((size_t)6 * NPOS * DD * 2);
  float*  Vf   = (float*) alloc((size_t)6 * NPOS * DD * 4);
  bf16_t* VtG  = (bf16_t*)alloc((size_t)6 * DD * NPOS * 2);
  bf16_t* CTXb = (bf16_t*)alloc((size_t)6 * NPOS * DD * 2);
  float*  XB   = (float*) alloc((size_t)6 * NPOS * DD * 4);
  float*  cbG  = (float*) alloc((size_t)6 * NPOS * HH * 4);
  int*    CNTb = (int*)   alloc((size_t)6 * NPOS * 4);

  hipMemsetAsync(d_out, 0, (size_t)out_size * sizeof(float), stream);
  hist_kernel<<<6, 256, 0, stream>>>(fpos, tpos, CNTb);

  // fp32 -> bf16 conversions: hs + 8 weight matrices
  CvtBatch cvb{};
  cvb.d[0] = CvtDesc{hs, hsb, 3 * NPOS * DD / 8};
  const float* wsrc[8] = {Wq[0], Wk[0], Wv[0], Wd[0], Wq[1], Wk[1], Wv[1], Wd[1]};
  for (int i = 0; i < 8; ++i)
    cvb.d[1 + i] = CvtDesc{wsrc[i], Wb + (size_t)i * DD * DD, DD * DD / 8};
  cvt_bf16<<<dim3(64, 9), 256, 0, stream>>>(cvb);

  cb_kernel<<<192, 256, 0, stream>>>(hs, Wcb[0], Wcb[1], cbG);

  // projection GEMMs: Q (f32), K (bf16), V (f32 + bias) for each (b, ps)
  MBatch gb{};
  int n = 0;
  for (int b = 0; b < 3; ++b)
    for (int p = 0; p < 2; ++p) {
      const int pd = b * 2 + p;
      const bf16_t* A = hsb + (size_t)b * NPOS * DD;
      const size_t o = (size_t)pd * NPOS * DD;
      gb.d[n++] = MDesc{A, Wb + (size_t)(p * 4 + 0) * DD * DD, nullptr, Qf + o, 0};
      gb.d[n++] = MDesc{A, Wb + (size_t)(p * 4 + 1) * DD * DD, nullptr, Kb + o, 1};
      gb.d[n++] = MDesc{A, Wb + (size_t)(p * 4 + 2) * DD * DD, bv[p],   Vf + o, 0};
    }
  mfma_gemm<<<dim3(24, 18), 256, 0, stream>>>(gb);

  vtrans<<<2304, 256, 0, stream>>>(Vf, VtG);

  attn_mfma<<<384, 256, 0, stream>>>(Qf, Kb, VtG, cbG, CNTb, mixp[0], mixp[1], CTXb);

  // output projection Wd per (b, dir) -> XB f32
  MBatch gd{};
  for (int b = 0; b < 3; ++b)
    for (int p = 0; p < 2; ++p) {
      const int pd = b * 2 + p;
      const size_t o = (size_t)pd * NPOS * DD;
      gd.d[pd] = MDesc{CTXb + o, Wb + (size_t)(p * 4 + 3) * DD * DD, bd[p], XB + o, 0};
    }
  mfma_gemm<<<dim3(24, 6), 256, 0, stream>>>(gd);

  ln_mean_kernel<<<24, 256, 0, stream>>>(hs, XB, CNTb, lng[0], lnb[0], lng[1], lnb[1],
                                         (float*)d_out);
}

// Round 3
// 286.060 us; speedup vs baseline: 5.9198x; 1.3735x over previous
//
#include <hip/hip_runtime.h>
#include <math.h>

#define DD 768
#define HH 16
#define DHH 48
#define NPOS 512
#define NIDX 2048
#define INV_SCALE 0.14433756729740643f   // 1/sqrt(768/16)
#define LN_EPS 1e-5f

typedef __bf16 bf16_t;
typedef __bf16 bf16x8 __attribute__((ext_vector_type(8)));
typedef float f32x4 __attribute__((ext_vector_type(4)));

__device__ __forceinline__ void g2lds16(const void* g, void* l) {
  __builtin_amdgcn_global_load_lds((const __attribute__((address_space(1))) void*)g,
                                   (__attribute__((address_space(3))) void*)l, 16, 0, 0);
}

// ---------------------------------------------------------------------------
// prep: blocks 0-5 hist | 6-581 fp32->bf16 cvt | 582-773 content-bias GEMV
// ---------------------------------------------------------------------------
struct CvtDesc { const float* src; bf16_t* dst; int n8; };
struct CvtBatch { CvtDesc d[9]; };

__global__ __launch_bounds__(256) void prep(const int* __restrict__ fpos,
                                            const int* __restrict__ tpos,
                                            int* __restrict__ CNT, CvtBatch cvb,
                                            const float* __restrict__ hs,
                                            const float* __restrict__ Wcb0,
                                            const float* __restrict__ Wcb1,
                                            float* __restrict__ cbG) {
  const int bid = blockIdx.x;
  const int tid = threadIdx.x;
  __shared__ int shist[NPOS];
  if (bid < 6) {
    const int b = bid >> 1, which = bid & 1;
    const int* src = (which ? tpos : fpos) + b * NIDX;
    for (int i = tid; i < NPOS; i += 256) shist[i] = 0;
    __syncthreads();
    for (int i = tid; i < NIDX; i += 256) atomicAdd(&shist[src[i] & (NPOS - 1)], 1);
    __syncthreads();
    for (int i = tid; i < NPOS; i += 256) CNT[bid * NPOS + i] = shist[i];
  } else if (bid < 582) {
    const CvtDesc de = cvb.d[(bid - 6) >> 6];
    for (int i = ((bid - 6) & 63) * 256 + tid; i < de.n8; i += 64 * 256) {
      const f32x4 a = *(const f32x4*)(de.src + (size_t)i * 8);
      const f32x4 b = *(const f32x4*)(de.src + (size_t)i * 8 + 4);
      bf16_t t[8];
#pragma unroll
      for (int e = 0; e < 4; ++e) { t[e] = (bf16_t)a[e]; t[4 + e] = (bf16_t)b[e]; }
      *(bf16x8*)(de.dst + (size_t)i * 8) = *(bf16x8*)t;
    }
  } else {
    const int g = bid - 582;               // 6*32
    const int pd = g >> 5, t0 = (g & 31) * 16;
    const int b = pd >> 1;
    const float* W = (pd & 1) ? Wcb1 : Wcb0;
    const int tl = tid >> 4, hh = tid & 15;
    const float* hrow = hs + ((size_t)b * NPOS + t0 + tl) * DD;
    const float* wrow = W + hh * DD;
    float s = 0.f;
    for (int k = 0; k < DD; k += 4) {
      const f32x4 a = *(const f32x4*)(hrow + k);
      const f32x4 bq = *(const f32x4*)(wrow + k);
      s += a[0] * bq[0] + a[1] * bq[1] + a[2] * bq[2] + a[3] * bq[3];
    }
    cbG[((size_t)pd * NPOS + t0 + tl) * HH + hh] = s;
  }
}

// ---------------------------------------------------------------------------
// MFMA GEMM: C[512 x 768] = A[512 x 768]bf16 @ B[768 x 768]bf16^T + bias
// ---------------------------------------------------------------------------
struct MDesc { const bf16_t* A; const bf16_t* B; const float* bias; void* C; int out_bf16; };
struct MBatch { MDesc d[18]; };

__global__ __launch_bounds__(256, 2) void mfma_gemm(MBatch batch) {
  const MDesc de = batch.d[blockIdx.y];
  const int mt = blockIdx.x & 3, nt = blockIdx.x >> 2;   // 4 x 6
  const int m0 = mt * 128, n0 = nt * 128;

  __shared__ bf16_t At[4096];
  __shared__ bf16_t Bt[4096];

  const int tid = threadIdx.x;
  const int w = tid >> 6, lane = tid & 63;
  const int wm = w >> 1, wn = w & 1;
  const int lm = lane & 15, lq = lane >> 4;

  f32x4 acc[4][4] = {};

  for (int k0 = 0; k0 < 768; k0 += 32) {
    __syncthreads();
    {
      const int lqq = lane & 3, lr = lane >> 2;
#pragma unroll
      for (int i = 0; i < 2; ++i) {
        const int issue = w + i * 4;
        const int row = issue * 16 + lr;
        g2lds16(de.A + (size_t)(m0 + row) * 768 + k0 + lqq * 8, At + issue * 512);
        g2lds16(de.B + (size_t)(n0 + row) * 768 + k0 + lqq * 8, Bt + issue * 512);
      }
    }
    __syncthreads();
    bf16x8 af[4], bfr[4];
#pragma unroll
    for (int f = 0; f < 4; ++f) {
      af[f] = *(const bf16x8*)(At + (wm * 64 + f * 16 + lm) * 32 + lq * 8);
      bfr[f] = *(const bf16x8*)(Bt + (wn * 64 + f * 16 + lm) * 32 + lq * 8);
    }
#pragma unroll
    for (int i = 0; i < 4; ++i)
#pragma unroll
      for (int j = 0; j < 4; ++j)
        acc[i][j] = __builtin_amdgcn_mfma_f32_16x16x32_bf16(af[i], bfr[j], acc[i][j], 0, 0, 0);
  }

#pragma unroll
  for (int i = 0; i < 4; ++i) {
    const int rbase = m0 + wm * 64 + i * 16 + lq * 4;
#pragma unroll
    for (int j = 0; j < 4; ++j) {
      const int c = n0 + wn * 64 + j * 16 + lm;
      const float bv = de.bias ? de.bias[c] : 0.f;
#pragma unroll
      for (int r = 0; r < 4; ++r) {
        const float v = acc[i][j][r] + bv;
        if (de.out_bf16) ((bf16_t*)de.C)[(size_t)(rbase + r) * 768 + c] = (bf16_t)v;
        else             ((float*)de.C)[(size_t)(rbase + r) * 768 + c] = v;
      }
    }
  }
}

// ---------------------------------------------------------------------------
// Transpose V bf16 [pd][t][d] -> Vt bf16 [pd][d][t]
// ---------------------------------------------------------------------------
__global__ __launch_bounds__(256) void vtrans(const bf16_t* __restrict__ V,
                                              bf16_t* __restrict__ Vt) {
  const int g = blockIdx.x;               // 6*24*16
  const int tt = g & 15;
  const int rem = g >> 4;
  const int dt = rem % 24, pd = rem / 24;
  const int t0 = tt * 32, d0 = dt * 32;
  __shared__ bf16_t tile[32][34];
  const int c = threadIdx.x & 31, r0 = threadIdx.x >> 5;
#pragma unroll
  for (int i = 0; i < 4; ++i) {
    const int r = r0 + i * 8;
    tile[c][r] = V[((size_t)pd * NPOS + t0 + r) * DD + d0 + c];
  }
  __syncthreads();
#pragma unroll
  for (int i = 0; i < 4; ++i) {
    const int r = r0 + i * 8;
    Vt[((size_t)pd * DD + d0 + r) * NPOS + t0 + c] = tile[r][c];
  }
}

// ---------------------------------------------------------------------------
// Fused MFMA attention per (pd, h, 64-row f-tile). m97-style K-loop with
// g2lds16 staging; mix applied at A-fragment; count folded into bias via log;
// PV via MFMA with ones-row for the softmax denominator.
// ---------------------------------------------------------------------------
__global__ __launch_bounds__(256, 3) void attn_mfma(
    const bf16_t* __restrict__ Qg, const bf16_t* __restrict__ Kg,
    const bf16_t* __restrict__ Vt, const float* __restrict__ cbG,
    const int* __restrict__ CNT, const float* __restrict__ mix0,
    const float* __restrict__ mix1, bf16_t* __restrict__ CTX) {
  const int bid = blockIdx.x;             // 6*16*8 = 768
  const int ft = bid & 7, h = (bid >> 3) & 15, pd = bid >> 7;
  const int dir = pd & 1;
  const int f0 = ft * 64;

  __shared__ bf16_t At[64 * 32];          // 4 KB   (g2lds, packed)
  __shared__ bf16_t Bt[128 * 32];         // 8 KB   (g2lds, packed)
  __shared__ bf16_t P[64 * 136];          // 17 KB  (stride 136: <=2-way)
  __shared__ bf16_t Vs[64 * 136];         // 17 KB  (rows 0-47 V, 48 ones, rest 0)
  __shared__ float mixs[768];             // 3 KB
  __shared__ float cbw[512];              // 2 KB   cb*inv_scale + log(cnt)
  __shared__ float rowl[64];              // total 52480 B -> 3 blocks/CU

  const int tid = threadIdx.x;
  const int w = tid >> 6, lane = tid & 63;
  const bf16_t* Qp = Qg + (size_t)pd * NPOS * DD;
  const bf16_t* Kp = Kg + (size_t)pd * NPOS * DD;
  const bf16_t* Vp = Vt + (size_t)pd * DD * NPOS + (size_t)h * DHH * NPOS;
  const float* mix = (dir ? mix1 : mix0) + h * DD;
  const int* cnt = CNT + ((pd & ~1) + (1 - dir)) * NPOS;  // to-side counts

  for (int i = tid; i < 768; i += 256) mixs[i] = mix[i];
  for (int i = tid; i < 512; i += 256)
    cbw[i] = cbG[((size_t)pd * NPOS + i) * HH + h] * INV_SCALE + __logf((float)cnt[i]);
  for (int i = tid; i < 16 * 136; i += 256) {
    const int r = i / 136, c = i % 136;
    Vs[(48 + r) * 136 + c] = (bf16_t)((r == 0 && c < 128) ? 1.f : 0.f);
  }
  __syncthreads();

  const int wm = w >> 1, wn = w & 1;
  const int lm = lane & 15, lq = lane >> 4;
  const int sr = lane >> 2, sq = lane & 3;   // staging row/chunk

  f32x4 pv[4] = {};                       // rows w*16..+15, cols 0..63

  for (int jt = 0; jt < 4; ++jt) {
    const int j0 = jt * 128;
    f32x4 sa[2][4] = {};

    for (int k0 = 0; k0 < DD; k0 += 32) {
      __syncthreads();
#pragma unroll
      for (int c = 0; c < 3; ++c) {
        const int issue = w + c * 4;     // 0..11, wave-uniform
        if (issue < 4)
          g2lds16(Qp + (size_t)(f0 + issue * 16 + sr) * DD + k0 + sq * 8, At + issue * 512);
        else {
          const int e = issue - 4;
          g2lds16(Kp + (size_t)(j0 + e * 16 + sr) * DD + k0 + sq * 8, Bt + e * 512);
        }
      }
      __syncthreads();
      const f32x4 mxa = *(const f32x4*)&mixs[k0 + lq * 8];
      const f32x4 mxb = *(const f32x4*)&mixs[k0 + lq * 8 + 4];
      bf16x8 af[2], bfr[4];
#pragma unroll
      for (int i = 0; i < 2; ++i) {
        const bf16x8 q = *(const bf16x8*)(At + (wm * 32 + i * 16 + lm) * 32 + lq * 8);
        bf16_t t[8];
#pragma unroll
        for (int e = 0; e < 4; ++e) {
          t[e]     = (bf16_t)((float)q[e] * mxa[e]);
          t[4 + e] = (bf16_t)((float)q[4 + e] * mxb[e]);
        }
        af[i] = *(bf16x8*)t;
      }
#pragma unroll
      for (int j = 0; j < 4; ++j)
        bfr[j] = *(const bf16x8*)(Bt + (wn * 64 + j * 16 + lm) * 32 + lq * 8);
#pragma unroll
      for (int i = 0; i < 2; ++i)
#pragma unroll
        for (int j = 0; j < 4; ++j)
          sa[i][j] = __builtin_amdgcn_mfma_f32_16x16x32_bf16(af[i], bfr[j], sa[i][j], 0, 0, 0);
    }
    __syncthreads();

    // p = exp(s*inv_scale + cb*inv_scale + log(cnt))
#pragma unroll
    for (int j = 0; j < 4; ++j) {
      const int col = wn * 64 + j * 16 + lm;
      const float cb = cbw[j0 + col];
#pragma unroll
      for (int i = 0; i < 2; ++i) {
        const int rbase = wm * 32 + i * 16 + lq * 4;
#pragma unroll
        for (int r = 0; r < 4; ++r)
          P[(rbase + r) * 136 + col] = (bf16_t)__expf(sa[i][j][r] * INV_SCALE + cb);
      }
    }
    // stage V^T rows 0..47, cols j0..j0+127
    for (int i = tid; i < 48 * 16; i += 256) {
      const int r = i >> 4, cc = i & 15;
      *(bf16x8*)(Vs + r * 136 + cc * 8) = *(const bf16x8*)(Vp + (size_t)r * NPOS + j0 + cc * 8);
    }
    __syncthreads();

#pragma unroll
    for (int kk = 0; kk < 4; ++kk) {
      const bf16x8 pa = *(const bf16x8*)(P + (w * 16 + lm) * 136 + kk * 32 + lq * 8);
#pragma unroll
      for (int j = 0; j < 4; ++j) {
        const bf16x8 pb = *(const bf16x8*)(Vs + (j * 16 + lm) * 136 + kk * 32 + lq * 8);
        pv[j] = __builtin_amdgcn_mfma_f32_16x16x32_bf16(pa, pb, pv[j], 0, 0, 0);
      }
    }
  }

  // epilogue: col 48 of D (j=3, lm=0) is the row denominator
  if (lm == 0) {
#pragma unroll
    for (int r = 0; r < 4; ++r) rowl[w * 16 + lq * 4 + r] = pv[3][r];
  }
  __syncthreads();
#pragma unroll
  for (int j = 0; j < 3; ++j) {
#pragma unroll
    for (int r = 0; r < 4; ++r) {
      const int fr = w * 16 + lq * 4 + r;
      CTX[((size_t)pd * NPOS + f0 + fr) * DD + h * DHH + j * 16 + lm] =
          (bf16_t)(pv[j][r] / rowl[fr]);
    }
  }
}

// ---------------------------------------------------------------------------
// Residual + LayerNorm + count-weighted mean -> out[b][dir*768 .. +768]
// ---------------------------------------------------------------------------
__global__ __launch_bounds__(256) void ln_mean_kernel(
    const float* __restrict__ hs, const float* __restrict__ XB,
    const int* __restrict__ CNT,
    const float* __restrict__ lng0, const float* __restrict__ lnb0,
    const float* __restrict__ lng1, const float* __restrict__ lnb1,
    float* __restrict__ out) {
  const int blk = blockIdx.x;          // (b*2+dir)*16 + chunk, 96 blocks
  const int chunk = blk & 15;
  const int pd = blk >> 4;
  const int b = pd >> 1, dir = pd & 1;
  const float* lng = dir ? lng1 : lng0;
  const float* lnb = dir ? lnb1 : lnb0;
  const int* cnt = CNT + pd * NPOS;    // from-side counts
  const float* hb = hs + (size_t)b * NPOS * DD;
  const float* xb = XB + (size_t)pd * NPOS * DD;

  __shared__ float wacc[4][DD];
  const int tid = threadIdx.x;
  const int wave = tid >> 6, lane = tid & 63;
  for (int d0 = tid; d0 < 4 * DD; d0 += 256) ((float*)wacc)[d0] = 0.f;
  __syncthreads();

  float lg[12], lb[12];
#pragma unroll
  for (int qd = 0; qd < 12; ++qd) {
    lg[qd] = lng[lane + qd * 64];
    lb[qd] = lnb[lane + qd * 64];
  }

  for (int rr = 0; rr < 8; ++rr) {
    const int p = chunk * 32 + wave * 8 + rr;
    float x[12];
    float s = 0.f, ss = 0.f;
#pragma unroll
    for (int qd = 0; qd < 12; ++qd) {
      const int d0 = lane + qd * 64;
      const float xv = hb[(size_t)p * DD + d0] + xb[(size_t)p * DD + d0];
      x[qd] = xv; s += xv; ss += xv * xv;
    }
#pragma unroll
    for (int o = 1; o < 64; o <<= 1) {
      s += __shfl_xor(s, o);
      ss += __shfl_xor(ss, o);
    }
    const float mu = s * (1.f / 768.f);
    const float var = ss * (1.f / 768.f) - mu * mu;
    const float rstd = rsqrtf(var + LN_EPS);
    const float wgt = (float)cnt[p];
    if (wgt != 0.f) {
#pragma unroll
      for (int qd = 0; qd < 12; ++qd) {
        const int d0 = lane + qd * 64;
        wacc[wave][d0] += wgt * (lg[qd] * (x[qd] - mu) * rstd + lb[qd]);
      }
    }
  }
  __syncthreads();
  for (int d0 = tid; d0 < DD; d0 += 256) {
    const float t = wacc[0][d0] + wacc[1][d0] + wacc[2][d0] + wacc[3][d0];
    atomicAdd(&out[b * 1536 + dir * 768 + d0], t * (1.f / 2048.f));
  }
}

// ---------------------------------------------------------------------------
extern "C" void kernel_launch(void* const* d_in, const int* in_sizes, int n_in,
                              void* d_out, int out_size, void* d_ws, size_t ws_size,
                              hipStream_t stream) {
  const float* hs  = (const float*)d_in[0];
  const int* fpos  = (const int*)d_in[1];
  const int* tpos  = (const int*)d_in[2];

  const float* Wq[2]; const float* Wk[2]; const float* Wcb[2]; const float* Wv[2];
  const float* Wd[2]; const float* mixp[2];
  const float* bv[2]; const float* bd[2]; const float* lng[2]; const float* lnb[2];
  for (int p = 0; p < 2; ++p) {
    const int base = 3 + p * 10;
    Wq[p]   = (const float*)d_in[base + 0];
    Wk[p]   = (const float*)d_in[base + 1];
    Wcb[p]  = (const float*)d_in[base + 2];
    Wv[p]   = (const float*)d_in[base + 3];
    Wd[p]   = (const float*)d_in[base + 4];
    mixp[p] = (const float*)d_in[base + 5];
    bv[p]   = (const float*)d_in[base + 6];
    bd[p]   = (const float*)d_in[base + 7];
    lng[p]  = (const float*)d_in[base + 8];
    lnb[p]  = (const float*)d_in[base + 9];
  }

  char* wsp = (char*)d_ws;
  size_t off = 0;
  auto alloc = [&](size_t bytes) { char* p = wsp + off; off = (off + bytes + 255) & ~(size_t)255; return p; };
  bf16_t* hsb  = (bf16_t*)alloc((size_t)3 * NPOS * DD * 2);
  bf16_t* Wb   = (bf16_t*)alloc((size_t)8 * DD * DD * 2);   // Wq0,Wk0,Wv0,Wd0,Wq1,...
  bf16_t* Qbf  = (bf16_t*)alloc((size_t)6 * NPOS * DD * 2);
  bf16_t* Kbf  = (bf16_t*)alloc((size_t)6 * NPOS * DD * 2);
  bf16_t* Vbf  = (bf16_t*)alloc((size_t)6 * NPOS * DD * 2);
  bf16_t* VtG  = (bf16_t*)alloc((size_t)6 * DD * NPOS * 2);
  bf16_t* CTXb = (bf16_t*)alloc((size_t)6 * NPOS * DD * 2);
  float*  XB   = (float*) alloc((size_t)6 * NPOS * DD * 4);
  float*  cbG  = (float*) alloc((size_t)6 * NPOS * HH * 4);
  int*    CNTb = (int*)   alloc((size_t)6 * NPOS * 4);

  hipMemsetAsync(d_out, 0, (size_t)out_size * sizeof(float), stream);

  CvtBatch cvb{};
  cvb.d[0] = CvtDesc{hs, hsb, 3 * NPOS * DD / 8};
  const float* wsrc[8] = {Wq[0], Wk[0], Wv[0], Wd[0], Wq[1], Wk[1], Wv[1], Wd[1]};
  for (int i = 0; i < 8; ++i)
    cvb.d[1 + i] = CvtDesc{wsrc[i], Wb + (size_t)i * DD * DD, DD * DD / 8};
  prep<<<774, 256, 0, stream>>>(fpos, tpos, CNTb, cvb, hs, Wcb[0], Wcb[1], cbG);

  // projection GEMMs: Q/K/V all bf16 out
  MBatch gb{};
  int n = 0;
  for (int b = 0; b < 3; ++b)
    for (int p = 0; p < 2; ++p) {
      const int pd = b * 2 + p;
      const bf16_t* A = hsb + (size_t)b * NPOS * DD;
      const size_t o = (size_t)pd * NPOS * DD;
      gb.d[n++] = MDesc{A, Wb + (size_t)(p * 4 + 0) * DD * DD, nullptr, Qbf + o, 1};
      gb.d[n++] = MDesc{A, Wb + (size_t)(p * 4 + 1) * DD * DD, nullptr, Kbf + o, 1};
      gb.d[n++] = MDesc{A, Wb + (size_t)(p * 4 + 2) * DD * DD, bv[p],   Vbf + o, 1};
    }
  mfma_gemm<<<dim3(24, 18), 256, 0, stream>>>(gb);

  vtrans<<<2304, 256, 0, stream>>>(Vbf, VtG);

  attn_mfma<<<768, 256, 0, stream>>>(Qbf, Kbf, VtG, cbG, CNTb, mixp[0], mixp[1], CTXb);

  MBatch gd{};
  for (int b = 0; b < 3; ++b)
    for (int p = 0; p < 2; ++p) {
      const int pd = b * 2 + p;
      const size_t o = (size_t)pd * NPOS * DD;
      gd.d[pd] = MDesc{CTXb + o, Wb + (size_t)(p * 4 + 3) * DD * DD, bd[p], XB + o, 0};
    }
  mfma_gemm<<<dim3(24, 6), 256, 0, stream>>>(gd);

  ln_mean_kernel<<<96, 256, 0, stream>>>(hs, XB, CNTb, lng[0], lnb[0], lng[1], lnb[1],
                                         (float*)d_out);
}